// Round 7
// baseline (116.009 us; speedup 1.0000x reference)
//
#include <hip/hip_runtime.h>
#include <math.h>

#define NN 100000   // N
#define NF 10       // n features
#define MC 8        // M_CLUSTERS
#define KK 16       // K neighbours
#define BB 4        // batch
#define MUF 20.0f

#define PB  200               // enc blocks (single-pass tiled)
#define JCH (NN / PB)         // 500 j per block
#define TRB ((NN + 255) / 256)  // 391 transpose blocks

__device__ __forceinline__ float frcp(float x) {
#if __has_builtin(__builtin_amdgcn_rcpf)
    return __builtin_amdgcn_rcpf(x);   // v_rcp_f32; wsum >= 7 so safe
#else
    return 1.0f / x;
#endif
}

// ---- Kernel A: single-pass enc partials (each j read ONCE) + W_dec transpose ----
// blocks [0,200): 40 accumulators/thread over a 500-j chunk -> part[pair*200+blk]
// blocks [200,591): transpose W_dec (n,N) -> Wt (N,16) 64B rows
template <bool TR>
__global__ __launch_bounds__(256) void k_prep(const float* __restrict__ x,
                                              const float* __restrict__ Wenc,
                                              const float* __restrict__ Wdec,
                                              float* __restrict__ part,
                                              float* __restrict__ Wt) {
    int blk = blockIdx.x;
    if (blk < PB) {
        int j0 = blk * JCH;
        float acc[BB * NF];
#pragma unroll
        for (int i = 0; i < BB * NF; ++i) acc[i] = 0.f;
        for (int jj = threadIdx.x; jj < JCH; jj += 256) {
            int j = j0 + jj;
            float xv[BB], wv[NF];
#pragma unroll
            for (int b = 0; b < BB; ++b) xv[b] = x[(size_t)b * NN + j];
#pragma unroll
            for (int c = 0; c < NF; ++c) wv[c] = Wenc[(size_t)c * NN + j];
#pragma unroll
            for (int b = 0; b < BB; ++b)
#pragma unroll
                for (int c = 0; c < NF; ++c)
                    acc[b * NF + c] = fmaf(xv[b], wv[c], acc[b * NF + c]);
        }
#pragma unroll
        for (int i = 0; i < BB * NF; ++i) {
            float v = acc[i];
#pragma unroll
            for (int off = 32; off; off >>= 1) v += __shfl_down(v, off, 64);
            acc[i] = v;
        }
        __shared__ float red[BB * NF][4];
        int lane = threadIdx.x & 63, w = threadIdx.x >> 6;
        if (lane == 0) {
#pragma unroll
            for (int i = 0; i < BB * NF; ++i) red[i][w] = acc[i];
        }
        __syncthreads();
        if (threadIdx.x < BB * NF)
            part[threadIdx.x * PB + blk] =
                red[threadIdx.x][0] + red[threadIdx.x][1] + red[threadIdx.x][2] + red[threadIdx.x][3];
    } else if (TR) {
        int j = (blk - PB) * 256 + threadIdx.x;
        if (j < NN) {
            float tmp[16];
#pragma unroll
            for (int c = 0; c < NF; ++c) tmp[c] = Wdec[(size_t)c * NN + j];
#pragma unroll
            for (int c = NF; c < 16; ++c) tmp[c] = 0.f;
            float4* o = (float4*)(Wt + (size_t)j * 16);
            o[0] = make_float4(tmp[0], tmp[1], tmp[2], tmp[3]);
            o[1] = make_float4(tmp[4], tmp[5], tmp[6], tmp[7]);
            o[2] = make_float4(tmp[8], tmp[9], tmp[10], tmp[11]);
            o[3] = make_float4(tmp[12], tmp[13], tmp[14], tmp[15]);
        }
    }
}

// ---- Kernel B: prologue (enc+dinv in LDS) + fused main, 2-way c-split ----
// g = global thread; j = g>>1, cg = g&1. cg0 handles c{0,1,2,3,8}, cg1 c{4,5,6,7,9},
// all 4 batches. Lane pair shares j; gathers are 1 float4 + 1 dword per neighbor.
template <bool TR>
__global__ __launch_bounds__(256) void k_main(const float* __restrict__ ndist,
                                              const int* __restrict__ nbid,
                                              const int* __restrict__ labels,
                                              const float* __restrict__ part,
                                              const float* __restrict__ Wbw,
                                              const float* __restrict__ Wsrc,
                                              float* __restrict__ out) {
    __shared__ float s_enc[BB * NF];         // 40
    __shared__ float s_dinv[BB * NF * MC];   // 320
    __shared__ float s_red[BB * NF][6];
    int tid = threadIdx.x;
    if (tid < 240) {
        int p = tid / 6, s = tid % 6;
        int i0 = s * 34, i1 = i0 + 34 > PB ? PB : i0 + 34;
        const float* pp = part + p * PB;
        float sum = 0.f;
        for (int i = i0; i < i1; ++i) sum += pp[i];
        s_red[p][s] = sum;
    }
    __syncthreads();
    if (tid < BB * NF) {
        float s = 0.f;
#pragma unroll
        for (int i = 0; i < 6; ++i) s += s_red[tid][i];
        s_enc[tid] = s;
    }
    __syncthreads();
    for (int t = tid; t < BB * NF * MC; t += 256) {
        int b = t / (NF * MC);
        int r = t % (NF * MC);               // r = c*MC + m
        float z = 0.f;
#pragma unroll
        for (int c = 0; c < NF; ++c) z = fmaf(s_enc[b * NF + c], Wbw[r * NF + c], z);
        float sig = 1.f / (1.f + __expf(-z));
        const float lo = (float)(4.0 / 60.0 / 20.0);
        const float sc = (float)(1.0 / 60.0 - 4.0 / 60.0 / 20.0);
        float bwv = fmaf(sc, sig, lo) * MUF;
        s_dinv[t] = frcp(bwv * bwv);
    }
    __syncthreads();

    int g = blockIdx.x * 256 + tid;
    int j = g >> 1;
    if (j >= NN) return;
    int cg = g & 1;
    int cbase = cg * 4;       // c0..3 or c4..7
    int cext  = 8 + cg;       // c8 or c9

    int lab = labels[j];
    float dv[BB][5];
#pragma unroll
    for (int b = 0; b < BB; ++b) {
#pragma unroll
        for (int i = 0; i < 4; ++i)
            dv[b][i] = s_dinv[b * (NF * MC) + (cbase + i) * MC + lab];
        dv[b][4] = s_dinv[b * (NF * MC) + cext * MC + lab];
    }

    const float4* dp = (const float4*)(ndist + (size_t)j * KK);
    float4 q0 = dp[0], q1 = dp[1], q2 = dp[2], q3 = dp[3];
    const int4* np = (const int4*)(nbid + (size_t)j * KK);
    int4 i0v = np[0], i1v = np[1], i2v = np[2], i3v = np[3];
    float nd[KK] = {q0.x, q0.y, q0.z, q0.w, q1.x, q1.y, q1.z, q1.w,
                    q2.x, q2.y, q2.z, q2.w, q3.x, q3.y, q3.z, q3.w};
    int nb[KK] = {i0v.x, i0v.y, i0v.z, i0v.w, i1v.x, i1v.y, i1v.z, i1v.w,
                  i2v.x, i2v.y, i2v.z, i2v.w, i3v.x, i3v.y, i3v.z, i3v.w};

    float ws[BB][5], sm[BB][5];
#pragma unroll
    for (int b = 0; b < BB; ++b)
#pragma unroll
        for (int i = 0; i < 5; ++i) { ws[b][i] = 0.f; sm[b][i] = 0.f; }

#pragma unroll
    for (int k = 0; k < KK; ++k) {
        float d = nd[k];
        float dd = d * d;
        float bas[5];
        if (TR) {
            const float* row = Wsrc + (size_t)(unsigned)nb[k] * 16;
            float4 bq = ((const float4*)row)[cg];    // cg0: c0-3, cg1: c4-7
            float be = row[cext];                    // c8 or c9
            bas[0] = bq.x; bas[1] = bq.y; bas[2] = bq.z; bas[3] = bq.w; bas[4] = be;
        } else {
#pragma unroll
            for (int i = 0; i < 4; ++i)
                bas[i] = Wsrc[(size_t)(cbase + i) * NN + (unsigned)nb[k]];
            bas[4] = Wsrc[(size_t)cext * NN + (unsigned)nb[k]];
        }
#pragma unroll
        for (int i = 0; i < 5; ++i)
#pragma unroll
            for (int b = 0; b < BB; ++b) {
                float w = fmaxf(fmaf(-dd, dv[b][i], 1.f), 0.f);
                ws[b][i] += w;
                sm[b][i] = fmaf(w, bas[i], sm[b][i]);
            }
    }

    float pbv[BB];
#pragma unroll
    for (int b = 0; b < BB; ++b) {
        float acc = 0.f;
#pragma unroll
        for (int i = 0; i < 4; ++i)
            acc = fmaf(s_enc[b * NF + cbase + i], sm[b][i] * frcp(ws[b][i]), acc);
        acc = fmaf(s_enc[b * NF + cext], sm[b][4] * frcp(ws[b][4]), acc);
        pbv[b] = acc;
    }
#pragma unroll
    for (int b = 0; b < BB; ++b) pbv[b] += __shfl_xor(pbv[b], 1, 64);
    if (cg == 0) {
#pragma unroll
        for (int b = 0; b < BB; ++b) out[(size_t)b * NN + j] = pbv[b];
    }
}

extern "C" void kernel_launch(void* const* d_in, const int* in_sizes, int n_in,
                              void* d_out, int out_size, void* d_ws, size_t ws_size,
                              hipStream_t stream) {
    const float* x      = (const float*)d_in[0];
    const float* Wenc   = (const float*)d_in[1];
    const float* Wdec   = (const float*)d_in[2];
    const float* Wbw    = (const float*)d_in[3];
    const float* ndist  = (const float*)d_in[4];
    const int*   nbid   = (const int*)d_in[5];
    const int*   labels = (const int*)d_in[6];
    float* out = (float*)d_out;

    float* part = (float*)d_ws;                       // 40*200 floats = 32KB
    float* Wt   = (float*)((char*)d_ws + 32768);      // N*16 floats (6.4 MB)
    size_t need = 32768 + (size_t)NN * 16 * sizeof(float);
    bool tr = (ws_size >= need);

    int main_blocks = (NN * 2 + 255) / 256;           // 782

    if (tr) {
        k_prep<true><<<PB + TRB, 256, 0, stream>>>(x, Wenc, Wdec, part, Wt);
        k_main<true><<<main_blocks, 256, 0, stream>>>(ndist, nbid, labels, part, Wbw, Wt, out);
    } else {
        k_prep<false><<<PB, 256, 0, stream>>>(x, Wenc, Wdec, part, nullptr);
        k_main<false><<<main_blocks, 256, 0, stream>>>(ndist, nbid, labels, part, Wbw, Wdec, out);
    }
}